// Round 5
// baseline (536.630 us; speedup 1.0000x reference)
//
#include <hip/hip_runtime.h>
#include <hip/hip_bf16.h>

#define NEG_SLOPE 0.2f
#define LRELU(v) ((v) > 0.f ? (v) : NEG_SLOPE * (v))
#define BBITS 7
#define BSZ 128  // nodes per bucket

static inline int cdiv(int a, int b) { return (a + b - 1) / b; }

// =================== wave-wide butterfly reductions (64 lanes) ===================
__device__ __forceinline__ float wmax(float v) {
#pragma unroll
    for (int o = 32; o; o >>= 1) v = fmaxf(v, __shfl_xor(v, o));
    return v;
}
__device__ __forceinline__ float wsum(float v) {
#pragma unroll
    for (int o = 32; o; o >>= 1) v += __shfl_xor(v, o);
    return v;
}

// =================== bucket-sort CSR build ===================
__global__ __launch_bounds__(256) void k_zero_int(int* p, int n) {
    int i = blockIdx.x * 256 + threadIdx.x;
    if (i < n) p[i] = 0;
}

__global__ __launch_bounds__(256) void k_bhist(const int* __restrict__ ei, int E, int ET, int NB,
                                               int* __restrict__ bcnt) {
    extern __shared__ int hist[];
    for (int i = threadIdx.x; i < NB; i += 256) hist[i] = 0;
    __syncthreads();
    int stride = gridDim.x * 256;
    for (int i = blockIdx.x * 256 + threadIdx.x; i < ET; i += stride) {
        int d = (i < E) ? ei[E + i] : (i - E);  // self loops appended
        atomicAdd(&hist[d >> BBITS], 1);
    }
    __syncthreads();
    for (int i = threadIdx.x; i < NB; i += 256) {
        int c = hist[i];
        if (c) atomicAdd(&bcnt[i], c);
    }
}

__global__ void k_scan_small(const int* __restrict__ bcnt, int NB,
                             int* __restrict__ boff, int* __restrict__ bcur,
                             int* __restrict__ offs, int N, int ET) {
    extern __shared__ int sm[];
    for (int i = threadIdx.x; i < NB; i += blockDim.x) sm[i] = bcnt[i];
    __syncthreads();
    if (threadIdx.x == 0) {
        int run = 0;
        for (int i = 0; i < NB; i++) { int c = sm[i]; sm[i] = run; run += c; }
    }
    __syncthreads();
    for (int i = threadIdx.x; i < NB; i += blockDim.x) { boff[i] = sm[i]; bcur[i] = sm[i]; }
    if (threadIdx.x == 0) { boff[NB] = ET; offs[N] = ET; }
}

__global__ __launch_bounds__(256) void k_bscatter(const int* __restrict__ ei, int E, int ET, int NB,
                                                  int* __restrict__ bcur,
                                                  long long* __restrict__ tmp) {
    extern __shared__ int sm2[];
    int* hist = sm2;
    int* cur = sm2 + NB;
    const int CH = 4096;
    int c0 = blockIdx.x * CH;
    int c1 = min(ET, c0 + CH);
    for (int i = threadIdx.x; i < NB; i += 256) hist[i] = 0;
    __syncthreads();
    for (int i = c0 + threadIdx.x; i < c1; i += 256) {
        int d = (i < E) ? ei[E + i] : (i - E);
        atomicAdd(&hist[d >> BBITS], 1);
    }
    __syncthreads();
    for (int i = threadIdx.x; i < NB; i += 256) {
        int c = hist[i];
        cur[i] = c ? atomicAdd(&bcur[i], c) : 0;
    }
    __syncthreads();
    for (int i = c0 + threadIdx.x; i < c1; i += 256) {
        int s = (i < E) ? ei[i] : (i - E);
        int d = (i < E) ? ei[E + i] : (i - E);
        int pos = atomicAdd(&cur[d >> BBITS], 1);
        tmp[pos] = ((long long)d << 32) | (unsigned)s;
    }
}

__global__ __launch_bounds__(256) void k_csrfin(const long long* __restrict__ tmp,
                                                const int* __restrict__ boff, int NB, int N,
                                                int* __restrict__ offs, int* __restrict__ ssrc) {
    __shared__ int deg[BSZ], cur[BSZ], sc[BSZ];
    int b = blockIdx.x;
    int node0 = b << BBITS;
    int nn = min(BSZ, N - node0);
    int r0 = boff[b], r1 = boff[b + 1];
    int t = threadIdx.x;
    if (t < BSZ) deg[t] = 0;
    __syncthreads();
    for (int i = r0 + t; i < r1; i += 256) {
        int d = (int)(tmp[i] >> 32);
        atomicAdd(&deg[d - node0], 1);
    }
    __syncthreads();
    if (t < BSZ) sc[t] = deg[t];
    __syncthreads();
    for (int o = 1; o < BSZ; o <<= 1) {
        int v = 0;
        if (t < BSZ && t >= o) v = sc[t - o];
        __syncthreads();
        if (t < BSZ) sc[t] += v;
        __syncthreads();
    }
    if (t < BSZ) {
        int ex = sc[t] - deg[t];
        cur[t] = r0 + ex;
        if (t < nn) offs[node0 + t] = r0 + ex;
    }
    __syncthreads();
    for (int i = r0 + t; i < r1; i += 256) {
        long long v = tmp[i];
        int d = (int)(v >> 32);
        int s = (int)(v & 0xffffffffLL);
        int pos = atomicAdd(&cur[d - node0], 1);
        ssrc[pos] = s;
    }
}

// ======= GEMM + fused alpha projections: h[N,M] = x[N,128]@W, as/ad = h·a_src/a_dst =======
template <int M, int TR, int H>
__global__ __launch_bounds__(256) void k_gemm_alpha(const float* __restrict__ x,
                                                    const float* __restrict__ W,
                                                    const float* __restrict__ a_src,
                                                    const float* __restrict__ a_dst,
                                                    float* __restrict__ h,
                                                    float* __restrict__ as, float* __restrict__ ad,
                                                    int N) {
    __shared__ float xs[128 * TR];  // xs[k][r], full K staged once
    __shared__ float ws[64 * M];    // ws[k][j], one 64-row half of W at a time
    __shared__ float sAS[TR * H], sAD[TR * H];
    int t = threadIdx.x;
    int row0 = blockIdx.x * TR;

    {   // load x tile transposed
        int r = t % TR;
        int kv0 = t / TR;
        const int GK = 256 / TR;
        int row = row0 + r;
        for (int kv = kv0; kv < 32; kv += GK) {
            float4 v = make_float4(0.f, 0.f, 0.f, 0.f);
            if (row < N) v = *(const float4*)(x + (size_t)row * 128 + kv * 4);
            xs[(kv * 4 + 0) * TR + r] = v.x;
            xs[(kv * 4 + 1) * TR + r] = v.y;
            xs[(kv * 4 + 2) * TR + r] = v.z;
            xs[(kv * 4 + 3) * TR + r] = v.w;
        }
    }
    for (int i = t; i < TR * H; i += 256) { sAS[i] = 0.f; sAD[i] = 0.f; }

    constexpr int CQ = M / 4;
    int tx = t % CQ, ty = t / CQ;
    int j0 = tx * 4, r0 = ty * 4;
    float acc[4][4];
#pragma unroll
    for (int a = 0; a < 4; a++)
#pragma unroll
        for (int b = 0; b < 4; b++) acc[a][b] = 0.f;

    for (int ks = 0; ks < 128; ks += 64) {
        __syncthreads();
        const float4* wg = (const float4*)(W + (size_t)ks * M);
        float4* wl = (float4*)ws;
        for (int i = t; i < 64 * M / 4; i += 256) wl[i] = wg[i];
        __syncthreads();
#pragma unroll 8
        for (int k = 0; k < 64; k++) {
            float4 xv = *(const float4*)(xs + (ks + k) * TR + r0);
            float4 wv = *(const float4*)(ws + k * M + j0);
            float xr[4] = {xv.x, xv.y, xv.z, xv.w};
            float wr[4] = {wv.x, wv.y, wv.z, wv.w};
#pragma unroll
            for (int a = 0; a < 4; a++)
#pragma unroll
                for (int b = 0; b < 4; b++) acc[a][b] += xr[a] * wr[b];
        }
    }
    // store h tile + accumulate alpha partials into LDS
    float4 asv = *(const float4*)(a_src + j0);
    float4 adv = *(const float4*)(a_dst + j0);
    int hh = j0 >> 6;
#pragma unroll
    for (int a = 0; a < 4; a++) {
        int row = row0 + r0 + a;
        if (row < N)
            *(float4*)(h + (size_t)row * M + j0) =
                make_float4(acc[a][0], acc[a][1], acc[a][2], acc[a][3]);
        float ssum = acc[a][0] * asv.x + acc[a][1] * asv.y + acc[a][2] * asv.z + acc[a][3] * asv.w;
        float dsum = acc[a][0] * adv.x + acc[a][1] * adv.y + acc[a][2] * adv.z + acc[a][3] * adv.w;
        atomicAdd(&sAS[(r0 + a) * H + hh], ssum);
        atomicAdd(&sAD[(r0 + a) * H + hh], dsum);
    }
    __syncthreads();
    for (int i = t; i < TR * H; i += 256) {
        int row = row0 + i / H;
        if (row < N) {
            as[(size_t)row * H + (i % H)] = sAS[i];
            ad[(size_t)row * H + (i % H)] = sAD[i];
        }
    }
}

// =================== fused softmax + aggregation: one wave per dst node ===================
// Gather uses sub-wave float4 rows: G = 16*H lanes cover one source row (16 B/lane),
// EPW = 64/G edges per wave-wide load instruction; 4 group-loads batched in flight.
template <int H, bool ELU_ACT>
__global__ __launch_bounds__(256) void k_agg_fused(const int* __restrict__ offs,
                                                   const int* __restrict__ ssrc,
                                                   const float* __restrict__ h,
                                                   const float* __restrict__ as,
                                                   const float* __restrict__ ad,
                                                   const float* __restrict__ bias,
                                                   float* __restrict__ z, int N) {
    constexpr int G = 16 * H;     // lanes per source row
    constexpr int EPW = 64 / G;   // edges per wave-wide load
    constexpr int NBG = 4;        // group-loads batched
    int d = (blockIdx.x * 256 + threadIdx.x) >> 6;
    int lane = threadIdx.x & 63;
    if (d >= N) return;
    int cpos = lane % G;          // 4-float chunk index within row
    int sub = lane / G;           // which edge of the group
    int hself = cpos >> 4;        // head owning this lane's channels (0 if H==1)

    float adh[H], m[H], den[H];
    float4 acc = make_float4(0.f, 0.f, 0.f, 0.f);
#pragma unroll
    for (int hh = 0; hh < H; hh++) {
        adh[hh] = ad[(size_t)d * H + hh];
        m[hh] = -1e30f; den[hh] = 0.f;
    }

    int e0 = offs[d], e1 = offs[d + 1];
    for (int cb = e0; cb < e1; cb += 64) {
        int ne = min(64, e1 - cb);
        int s_l = 0;
        float eh[H];
#pragma unroll
        for (int hh = 0; hh < H; hh++) eh[hh] = -1e30f;
        if (lane < ne) {
            s_l = ssrc[cb + lane];
#pragma unroll
            for (int hh = 0; hh < H; hh++) {
                float e = as[(size_t)s_l * H + hh] + adh[hh];
                eh[hh] = LRELU(e);
            }
        }
        float p[H], sc[H];
#pragma unroll
        for (int hh = 0; hh < H; hh++) {
            float cm = wmax(eh[hh]);
            float nm = fmaxf(m[hh], cm);
            sc[hh] = __expf(m[hh] - nm);  // first chunk: 0
            p[hh] = (lane < ne) ? __expf(eh[hh] - nm) : 0.f;
            den[hh] = den[hh] * sc[hh] + wsum(p[hh]);
            m[hh] = nm;
        }
        float scl = (H == 1) ? sc[0] : (hself == 0 ? sc[0] : sc[1]);
        acc.x *= scl; acc.y *= scl; acc.z *= scl; acc.w *= scl;

        // batched sub-wave float4 gather
        for (int j = 0; j < ne; j += NBG * EPW) {
            float4 hv[NBG];
            float pm[NBG];
#pragma unroll
            for (int g = 0; g < NBG; g++) {
                int eidx = j + g * EPW + sub;
                bool ok = eidx < ne;
                int el = eidx & 63;
                int s_e = __shfl(s_l, el);
                float pv;
                if (H == 2) {
                    float p0 = __shfl(p[0], el);
                    float p1 = __shfl(p[1], el);
                    pv = (hself == 0) ? p0 : p1;
                } else {
                    pv = __shfl(p[0], el);
                }
                pm[g] = ok ? pv : 0.f;
                hv[g] = make_float4(0.f, 0.f, 0.f, 0.f);
                if (ok) hv[g] = *(const float4*)(h + (size_t)s_e * (H * 64) + 4 * cpos);
            }
#pragma unroll
            for (int g = 0; g < NBG; g++) {
                acc.x += pm[g] * hv[g].x;
                acc.y += pm[g] * hv[g].y;
                acc.z += pm[g] * hv[g].z;
                acc.w += pm[g] * hv[g].w;
            }
        }
    }
    // fold sub-wave partials: lanes sharing cpos sum across sub
#pragma unroll
    for (int o = G; o < 64; o <<= 1) {
        acc.x += __shfl_xor(acc.x, o);
        acc.y += __shfl_xor(acc.y, o);
        acc.z += __shfl_xor(acc.z, o);
        acc.w += __shfl_xor(acc.w, o);
    }
    if (lane < G) {
        float inv = 1.f / den[hself];
        float4 bv = *(const float4*)(bias + 4 * cpos);
        float4 v;
        v.x = acc.x * inv + bv.x;
        v.y = acc.y * inv + bv.y;
        v.z = acc.z * inv + bv.z;
        v.w = acc.w * inv + bv.w;
        if (ELU_ACT) {
            v.x = v.x > 0.f ? v.x : expm1f(v.x);
            v.y = v.y > 0.f ? v.y : expm1f(v.y);
            v.z = v.z > 0.f ? v.z : expm1f(v.z);
            v.w = v.w > 0.f ? v.w : expm1f(v.w);
        }
        *(float4*)(z + (size_t)d * (H * 64) + 4 * cpos) = v;
    }
}

// =================== decode: dot of endpoint embeddings ===================
__global__ __launch_bounds__(256) void k_decode(const int* __restrict__ eli,
                                                const float* __restrict__ z,
                                                float* __restrict__ out, int EL) {
    int wid = (blockIdx.x * 256 + threadIdx.x) >> 6;
    int lane = threadIdx.x & 63;
    if (wid >= EL) return;
    int a = eli[wid], b = eli[EL + wid];
    float p = z[(size_t)a * 64 + lane] * z[(size_t)b * 64 + lane];
#pragma unroll
    for (int off = 32; off; off >>= 1) p += __shfl_down(p, off);
    if (lane == 0) out[wid] = p;
}

extern "C" void kernel_launch(void* const* d_in, const int* in_sizes, int n_in,
                              void* d_out, int out_size, void* d_ws, size_t ws_size,
                              hipStream_t stream) {
    const float* x   = (const float*)d_in[0];
    const int*   ei  = (const int*)d_in[1];
    const int*   eli = (const int*)d_in[2];
    const float* W1  = (const float*)d_in[3];
    const float* as1 = (const float*)d_in[4];
    const float* ad1 = (const float*)d_in[5];
    const float* b1  = (const float*)d_in[6];
    const float* W2  = (const float*)d_in[7];
    const float* as2 = (const float*)d_in[8];
    const float* ad2 = (const float*)d_in[9];
    const float* b2  = (const float*)d_in[10];

    int N  = in_sizes[0] / 128;
    int E  = in_sizes[1] / 2;
    int EL = in_sizes[2] / 2;
    int ET = E + N;
    int NB = cdiv(N, BSZ);

    char* ws = (char*)d_ws;
    size_t off = 0;
    auto alloc = [&](size_t nbytes) -> void* {
        void* p = ws + off;
        off += (nbytes + 255) & ~(size_t)255;
        return p;
    };
    float*    Hbuf = (float*)alloc((size_t)N * 128 * 4);  // h1 then h2
    float*    Zbuf = (float*)alloc((size_t)N * 128 * 4);  // z1 then z2 (TMP aliases this)
    float*    AS   = (float*)alloc((size_t)N * 2 * 4);
    float*    AD   = (float*)alloc((size_t)N * 2 * 4);
    int*      OFF  = (int*)alloc((size_t)(N + 1) * 4);
    int*      SSRC = (int*)alloc((size_t)ET * 4);
    int*      BCNT = (int*)alloc((size_t)NB * 4);
    int*      BOFF = (int*)alloc((size_t)(NB + 1) * 4);
    int*      BCUR = (int*)alloc((size_t)NB * 4);
    long long* TMP = (long long*)Zbuf;  // (d,s) pairs; Zbuf unused until k_agg L1

    // ---- CSR build via bucket sort (shared by both layers) ----
    k_zero_int<<<cdiv(NB, 256), 256, 0, stream>>>(BCNT, NB);
    k_bhist<<<256, 256, NB * 4, stream>>>(ei, E, ET, NB, BCNT);
    k_scan_small<<<1, 256, NB * 4, stream>>>(BCNT, NB, BOFF, BCUR, OFF, N, ET);
    k_bscatter<<<cdiv(ET, 4096), 256, 2 * NB * 4, stream>>>(ei, E, ET, NB, BCUR, TMP);
    k_csrfin<<<NB, 256, 0, stream>>>(TMP, BOFF, NB, N, OFF, SSRC);

    // ---- layer 1: heads=2, C=64, ELU ----
    k_gemm_alpha<128, 32, 2><<<cdiv(N, 32), 256, 0, stream>>>(x, W1, as1, ad1, Hbuf, AS, AD, N);
    k_agg_fused<2, true><<<cdiv(N, 4), 256, 0, stream>>>(OFF, SSRC, Hbuf, AS, AD, b1, Zbuf, N);

    // ---- layer 2: heads=1, C=64, no activation ----
    k_gemm_alpha<64, 64, 1><<<cdiv(N, 64), 256, 0, stream>>>(Zbuf, W2, as2, ad2, Hbuf, AS, AD, N);
    k_agg_fused<1, false><<<cdiv(N, 4), 256, 0, stream>>>(OFF, SSRC, Hbuf, AS, AD, b2, Zbuf, N);

    // ---- decode ----
    k_decode<<<cdiv(EL, 4), 256, 0, stream>>>(eli, Zbuf, (float*)d_out, EL);
}

// Round 6
// 470.927 us; speedup vs baseline: 1.1395x; 1.1395x over previous
//
#include <hip/hip_runtime.h>
#include <hip/hip_bf16.h>

#define NEG_SLOPE 0.2f
#define LRELU(v) ((v) > 0.f ? (v) : NEG_SLOPE * (v))
#define BBITS 7
#define BSZ 128  // nodes per bucket

typedef unsigned short ushort_t;
typedef unsigned int uint_t;

static inline int cdiv(int a, int b) { return (a + b - 1) / b; }

__device__ __forceinline__ float wsum(float v) {
#pragma unroll
    for (int o = 32; o; o >>= 1) v += __shfl_xor(v, o);
    return v;
}
__device__ __forceinline__ ushort_t f2bfbits(float f) {
    __hip_bfloat16 b = __float2bfloat16(f);
    return *reinterpret_cast<ushort_t*>(&b);
}
__device__ __forceinline__ float bf2f(ushort_t u) {
    return __uint_as_float(((uint_t)u) << 16);
}

// =================== bucket-sort CSR build ===================
__global__ __launch_bounds__(256) void k_zero_int(int* p, int n) {
    int i = blockIdx.x * 256 + threadIdx.x;
    if (i < n) p[i] = 0;
}

__global__ __launch_bounds__(256) void k_bhist(const int* __restrict__ ei, int E, int ET, int NB,
                                               int* __restrict__ bcnt) {
    extern __shared__ int hist[];
    for (int i = threadIdx.x; i < NB; i += 256) hist[i] = 0;
    __syncthreads();
    int stride = gridDim.x * 256;
    for (int i = blockIdx.x * 256 + threadIdx.x; i < ET; i += stride) {
        int d = (i < E) ? ei[E + i] : (i - E);  // self loops appended
        atomicAdd(&hist[d >> BBITS], 1);
    }
    __syncthreads();
    for (int i = threadIdx.x; i < NB; i += 256) {
        int c = hist[i];
        if (c) atomicAdd(&bcnt[i], c);
    }
}

__global__ void k_scan_small(const int* __restrict__ bcnt, int NB,
                             int* __restrict__ boff, int* __restrict__ bcur,
                             int* __restrict__ offs, int N, int ET) {
    extern __shared__ int sm[];
    for (int i = threadIdx.x; i < NB; i += blockDim.x) sm[i] = bcnt[i];
    __syncthreads();
    if (threadIdx.x == 0) {
        int run = 0;
        for (int i = 0; i < NB; i++) { int c = sm[i]; sm[i] = run; run += c; }
    }
    __syncthreads();
    for (int i = threadIdx.x; i < NB; i += blockDim.x) { boff[i] = sm[i]; bcur[i] = sm[i]; }
    if (threadIdx.x == 0) { boff[NB] = ET; offs[N] = ET; }
}

__global__ __launch_bounds__(256) void k_bscatter(const int* __restrict__ ei, int E, int ET, int NB,
                                                  int* __restrict__ bcur,
                                                  long long* __restrict__ tmp) {
    extern __shared__ int sm2[];
    int* hist = sm2;
    int* cur = sm2 + NB;
    const int CH = 4096;
    int c0 = blockIdx.x * CH;
    int c1 = min(ET, c0 + CH);
    for (int i = threadIdx.x; i < NB; i += 256) hist[i] = 0;
    __syncthreads();
    for (int i = c0 + threadIdx.x; i < c1; i += 256) {
        int d = (i < E) ? ei[E + i] : (i - E);
        atomicAdd(&hist[d >> BBITS], 1);
    }
    __syncthreads();
    for (int i = threadIdx.x; i < NB; i += 256) {
        int c = hist[i];
        cur[i] = c ? atomicAdd(&bcur[i], c) : 0;
    }
    __syncthreads();
    for (int i = c0 + threadIdx.x; i < c1; i += 256) {
        int s = (i < E) ? ei[i] : (i - E);
        int d = (i < E) ? ei[E + i] : (i - E);
        int pos = atomicAdd(&cur[d >> BBITS], 1);
        tmp[pos] = ((long long)d << 32) | (unsigned)s;
    }
}

__global__ __launch_bounds__(256) void k_csrfin(const long long* __restrict__ tmp,
                                                const int* __restrict__ boff, int NB, int N,
                                                int* __restrict__ offs, int* __restrict__ ssrc) {
    __shared__ int deg[BSZ], cur[BSZ], sc[BSZ];
    int b = blockIdx.x;
    int node0 = b << BBITS;
    int nn = min(BSZ, N - node0);
    int r0 = boff[b], r1 = boff[b + 1];
    int t = threadIdx.x;
    if (t < BSZ) deg[t] = 0;
    __syncthreads();
    for (int i = r0 + t; i < r1; i += 256) {
        int d = (int)(tmp[i] >> 32);
        atomicAdd(&deg[d - node0], 1);
    }
    __syncthreads();
    if (t < BSZ) sc[t] = deg[t];
    __syncthreads();
    for (int o = 1; o < BSZ; o <<= 1) {
        int v = 0;
        if (t < BSZ && t >= o) v = sc[t - o];
        __syncthreads();
        if (t < BSZ) sc[t] += v;
        __syncthreads();
    }
    if (t < BSZ) {
        int ex = sc[t] - deg[t];
        cur[t] = r0 + ex;
        if (t < nn) offs[node0 + t] = r0 + ex;
    }
    __syncthreads();
    for (int i = r0 + t; i < r1; i += 256) {
        long long v = tmp[i];
        int d = (int)(v >> 32);
        int s = (int)(v & 0xffffffffLL);
        int pos = atomicAdd(&cur[d - node0], 1);
        ssrc[pos] = s;
    }
}

// =================== GEMM: h[N,M] = x[N,128] @ W[128,M], h stored bf16 ===================
template <int M, int TR>
__global__ __launch_bounds__(256) void k_gemm(const float* __restrict__ x,
                                              const float* __restrict__ W,
                                              ushort_t* __restrict__ h, int N) {
    __shared__ float xs[128 * TR];  // xs[k][r], full K staged once
    __shared__ float ws[64 * M];    // ws[k][j], one 64-row half of W at a time
    int t = threadIdx.x;
    int row0 = blockIdx.x * TR;

    {   // load x tile transposed
        int r = t % TR;
        int kv0 = t / TR;
        const int GK = 256 / TR;
        int row = row0 + r;
        for (int kv = kv0; kv < 32; kv += GK) {
            float4 v = make_float4(0.f, 0.f, 0.f, 0.f);
            if (row < N) v = *(const float4*)(x + (size_t)row * 128 + kv * 4);
            xs[(kv * 4 + 0) * TR + r] = v.x;
            xs[(kv * 4 + 1) * TR + r] = v.y;
            xs[(kv * 4 + 2) * TR + r] = v.z;
            xs[(kv * 4 + 3) * TR + r] = v.w;
        }
    }

    constexpr int CQ = M / 4;
    int tx = t % CQ, ty = t / CQ;
    int j0 = tx * 4, r0 = ty * 4;
    float acc[4][4];
#pragma unroll
    for (int a = 0; a < 4; a++)
#pragma unroll
        for (int b = 0; b < 4; b++) acc[a][b] = 0.f;

    for (int ks = 0; ks < 128; ks += 64) {
        __syncthreads();
        const float4* wg = (const float4*)(W + (size_t)ks * M);
        float4* wl = (float4*)ws;
        for (int i = t; i < 64 * M / 4; i += 256) wl[i] = wg[i];
        __syncthreads();
#pragma unroll 8
        for (int k = 0; k < 64; k++) {
            float4 xv = *(const float4*)(xs + (ks + k) * TR + r0);
            float4 wv = *(const float4*)(ws + k * M + j0);
            float xr[4] = {xv.x, xv.y, xv.z, xv.w};
            float wr[4] = {wv.x, wv.y, wv.z, wv.w};
#pragma unroll
            for (int a = 0; a < 4; a++)
#pragma unroll
                for (int b = 0; b < 4; b++) acc[a][b] += xr[a] * wr[b];
        }
    }
#pragma unroll
    for (int a = 0; a < 4; a++) {
        int row = row0 + r0 + a;
        if (row < N) {
            ushort4 pk;
            pk.x = f2bfbits(acc[a][0]);
            pk.y = f2bfbits(acc[a][1]);
            pk.z = f2bfbits(acc[a][2]);
            pk.w = f2bfbits(acc[a][3]);
            *(ushort4*)(h + (size_t)row * M + j0) = pk;
        }
    }
}

// =================== per-node attention projections (bf16 h in, fp32 out) ==========
template <int H>
__global__ __launch_bounds__(256) void k_alpha(const ushort_t* __restrict__ h,
                                               const float* __restrict__ a_src,
                                               const float* __restrict__ a_dst,
                                               float* __restrict__ as, float* __restrict__ ad,
                                               int N) {
    int wid = (blockIdx.x * 256 + threadIdx.x) >> 6;
    int lane = threadIdx.x & 63;
    if (wid >= N * H) return;
    int n = wid / H, hh = wid % H;
    float v = bf2f(h[(size_t)n * (H * 64) + hh * 64 + lane]);
    float s = v * a_src[hh * 64 + lane];
    float d = v * a_dst[hh * 64 + lane];
#pragma unroll
    for (int off = 32; off; off >>= 1) { s += __shfl_down(s, off); d += __shfl_down(d, off); }
    if (lane == 0) { as[wid] = s; ad[wid] = d; }
}

// ======= fused softmax + aggregation: one wave per dst node, bf16 rows, no-max exp =======
// G = 8*H lanes cover one 16B-per-lane source row; EPW = 64/G edges per wave-wide load.
// p values staged in per-wave LDS (broadcast reads, conflict-free).
template <int H, bool ELU_ACT>
__global__ __launch_bounds__(256) void k_agg_fused(const int* __restrict__ offs,
                                                   const int* __restrict__ ssrc,
                                                   const ushort_t* __restrict__ h,
                                                   const float* __restrict__ as,
                                                   const float* __restrict__ ad,
                                                   const float* __restrict__ bias,
                                                   float* __restrict__ z, int N) {
    constexpr int G = 8 * H;     // lanes per source row (16 B each)
    constexpr int EPW = 64 / G;  // edges per wave-wide load
    constexpr int NBG = 4;       // group-loads batched in flight
    __shared__ float pl[4][64 * H];
    int d = (blockIdx.x * 256 + threadIdx.x) >> 6;
    int lane = threadIdx.x & 63;
    float* pw = pl[threadIdx.x >> 6];
    if (d >= N) return;
    int cpos = lane % G;         // 16B chunk index within row (channels 8*cpos..)
    int sub = lane / G;          // which edge of the load group
    int hself = (H == 2) ? (cpos >> 3) : 0;

    float adh[H], den[H];
#pragma unroll
    for (int hh = 0; hh < H; hh++) { adh[hh] = ad[(size_t)d * H + hh]; den[hh] = 0.f; }
    float acc[8];
#pragma unroll
    for (int i = 0; i < 8; i++) acc[i] = 0.f;

    int e0 = offs[d], e1 = offs[d + 1];
    for (int cb = e0; cb < e1; cb += 64) {
        int ne = min(64, e1 - cb);
        int s_l = 0;
        float p[H];
#pragma unroll
        for (int hh = 0; hh < H; hh++) p[hh] = 0.f;
        if (lane < ne) {
            s_l = ssrc[cb + lane];
            if (H == 2) {
                float2 av = ((const float2*)as)[s_l];
                float ea = av.x + adh[0];
                float eb = av.y + adh[1];
                p[0] = __expf(LRELU(ea));
                p[1] = __expf(LRELU(eb));
            } else {
                float ev = as[s_l] + adh[0];
                p[0] = __expf(LRELU(ev));
            }
        }
#pragma unroll
        for (int hh = 0; hh < H; hh++) den[hh] += wsum(p[hh]);
        if (H == 2) {
            pw[lane * 2] = p[0];
            pw[lane * 2 + 1] = p[1];
        } else {
            pw[lane] = p[0];
        }
        // gather: NBG group-loads in flight, then LDS p-read + unpack + FMA
        for (int j = 0; j < ne; j += NBG * EPW) {
            uint4 hv[NBG];
            int el[NBG];
            bool ok[NBG];
#pragma unroll
            for (int g = 0; g < NBG; g++) {
                int eidx = j + g * EPW + sub;
                el[g] = eidx & 63;
                ok[g] = eidx < ne;
                int s_e = __shfl(s_l, el[g]);
                hv[g] = make_uint4(0u, 0u, 0u, 0u);
                if (ok[g]) hv[g] = *(const uint4*)(h + (size_t)s_e * (H * 64) + cpos * 8);
            }
#pragma unroll
            for (int g = 0; g < NBG; g++) {
                float pv = ok[g] ? pw[el[g] * H + hself] : 0.f;
                acc[0] += pv * __uint_as_float(hv[g].x << 16);
                acc[1] += pv * __uint_as_float(hv[g].x & 0xffff0000u);
                acc[2] += pv * __uint_as_float(hv[g].y << 16);
                acc[3] += pv * __uint_as_float(hv[g].y & 0xffff0000u);
                acc[4] += pv * __uint_as_float(hv[g].z << 16);
                acc[5] += pv * __uint_as_float(hv[g].z & 0xffff0000u);
                acc[6] += pv * __uint_as_float(hv[g].w << 16);
                acc[7] += pv * __uint_as_float(hv[g].w & 0xffff0000u);
            }
        }
    }
    // fold sub-wave partials: lanes sharing cpos sum across sub
#pragma unroll
    for (int o = G; o < 64; o <<= 1)
#pragma unroll
        for (int i = 0; i < 8; i++) acc[i] += __shfl_xor(acc[i], o);
    if (lane < G) {
        float dsel = (H == 2 && hself) ? den[1] : den[0];
        float inv = 1.f / dsel;
        float vout[8];
#pragma unroll
        for (int i = 0; i < 8; i++) {
            vout[i] = acc[i] * inv + bias[cpos * 8 + i];
            if (ELU_ACT) vout[i] = vout[i] > 0.f ? vout[i] : expm1f(vout[i]);
        }
        float* zp = z + (size_t)d * (H * 64) + cpos * 8;
        *(float4*)zp = make_float4(vout[0], vout[1], vout[2], vout[3]);
        *(float4*)(zp + 4) = make_float4(vout[4], vout[5], vout[6], vout[7]);
    }
}

// =================== decode: dot of endpoint embeddings ===================
__global__ __launch_bounds__(256) void k_decode(const int* __restrict__ eli,
                                                const float* __restrict__ z,
                                                float* __restrict__ out, int EL) {
    int wid = (blockIdx.x * 256 + threadIdx.x) >> 6;
    int lane = threadIdx.x & 63;
    if (wid >= EL) return;
    int a = eli[wid], b = eli[EL + wid];
    float p = z[(size_t)a * 64 + lane] * z[(size_t)b * 64 + lane];
#pragma unroll
    for (int off = 32; off; off >>= 1) p += __shfl_down(p, off);
    if (lane == 0) out[wid] = p;
}

extern "C" void kernel_launch(void* const* d_in, const int* in_sizes, int n_in,
                              void* d_out, int out_size, void* d_ws, size_t ws_size,
                              hipStream_t stream) {
    const float* x   = (const float*)d_in[0];
    const int*   ei  = (const int*)d_in[1];
    const int*   eli = (const int*)d_in[2];
    const float* W1  = (const float*)d_in[3];
    const float* as1 = (const float*)d_in[4];
    const float* ad1 = (const float*)d_in[5];
    const float* b1  = (const float*)d_in[6];
    const float* W2  = (const float*)d_in[7];
    const float* as2 = (const float*)d_in[8];
    const float* ad2 = (const float*)d_in[9];
    const float* b2  = (const float*)d_in[10];

    int N  = in_sizes[0] / 128;
    int E  = in_sizes[1] / 2;
    int EL = in_sizes[2] / 2;
    int ET = E + N;
    int NB = cdiv(N, BSZ);

    char* ws = (char*)d_ws;
    size_t off = 0;
    auto alloc = [&](size_t nbytes) -> void* {
        void* p = ws + off;
        off += (nbytes + 255) & ~(size_t)255;
        return p;
    };
    ushort_t* Hbuf = (ushort_t*)alloc((size_t)N * 128 * 2);  // h1 then h2 (bf16)
    float*    Zbuf = (float*)alloc((size_t)N * 128 * 4);     // z1 then z2 (TMP aliases this)
    float*    AS   = (float*)alloc((size_t)N * 2 * 4);
    float*    AD   = (float*)alloc((size_t)N * 2 * 4);
    int*      OFF  = (int*)alloc((size_t)(N + 1) * 4);
    int*      SSRC = (int*)alloc((size_t)ET * 4);
    int*      BCNT = (int*)alloc((size_t)NB * 4);
    int*      BOFF = (int*)alloc((size_t)(NB + 1) * 4);
    int*      BCUR = (int*)alloc((size_t)NB * 4);
    long long* TMP = (long long*)Zbuf;  // (d,s) pairs; Zbuf unused until k_agg L1

    // ---- CSR build via bucket sort (shared by both layers) ----
    k_zero_int<<<cdiv(NB, 256), 256, 0, stream>>>(BCNT, NB);
    k_bhist<<<256, 256, NB * 4, stream>>>(ei, E, ET, NB, BCNT);
    k_scan_small<<<1, 256, NB * 4, stream>>>(BCNT, NB, BOFF, BCUR, OFF, N, ET);
    k_bscatter<<<cdiv(ET, 4096), 256, 2 * NB * 4, stream>>>(ei, E, ET, NB, BCUR, TMP);
    k_csrfin<<<NB, 256, 0, stream>>>(TMP, BOFF, NB, N, OFF, SSRC);

    // ---- layer 1: heads=2, C=64, ELU ----
    k_gemm<128, 32><<<cdiv(N, 32), 256, 0, stream>>>(x, W1, Hbuf, N);
    k_alpha<2><<<cdiv(N * 2, 4), 256, 0, stream>>>(Hbuf, as1, ad1, AS, AD, N);
    k_agg_fused<2, true><<<cdiv(N, 4), 256, 0, stream>>>(OFF, SSRC, Hbuf, AS, AD, b1, Zbuf, N);

    // ---- layer 2: heads=1, C=64, no activation ----
    k_gemm<64, 64><<<cdiv(N, 64), 256, 0, stream>>>(Zbuf, W2, Hbuf, N);
    k_alpha<1><<<cdiv(N, 4), 256, 0, stream>>>(Hbuf, as2, ad2, AS, AD, N);
    k_agg_fused<1, false><<<cdiv(N, 4), 256, 0, stream>>>(OFF, SSRC, Hbuf, AS, AD, b2, Zbuf, N);

    // ---- decode ----
    k_decode<<<cdiv(EL, 4), 256, 0, stream>>>(eli, Zbuf, (float*)d_out, EL);
}